// Round 12
// baseline (42.297 us; speedup 1.0000x reference)
//
#include <hip/hip_runtime.h>

// MTRNN single step. Live computation after DCE (reference returns only y):
//   io_new = tanh([x|io|cf] @ (0.5*[Wi2io | Wio2io+I | Wcf2io])^T + bsum)
//   y      = tanh(io_new @ Wio2o^T + bio2o)
// cf_new / cs_new dead. bf16 MFMA, f32 accumulate.
// r12: prep emits bf16 A (chunk-XOR pre-swizzled, for gl_lds) and B weights
// in MFMA-FRAG-CONTIGUOUS layout. gemm1 stages ONLY A through LDS (3-buf,
// counted vmcnt, 2 ahead); B-frags are read directly from global as one
// coalesced 1KB wave-load each (L1-resident) -> LDS-read issue drops 67%.

typedef float f32x4 __attribute__((ext_vector_type(4)));
typedef __bf16 bf16x4 __attribute__((ext_vector_type(4)));
typedef __bf16 bf16x8 __attribute__((ext_vector_type(8)));
typedef unsigned short u16x4 __attribute__((ext_vector_type(4)));

__device__ __forceinline__ unsigned short f2bf(float f) {
    unsigned u = __builtin_bit_cast(unsigned, f);
    u += 0x7FFFu + ((u >> 16) & 1u);
    return (unsigned short)(u >> 16);
}

__device__ __forceinline__ float tanh_fast(float x) {
    float e = __expf(2.0f * x);
    return 1.0f - 2.0f * __builtin_amdgcn_rcpf(e + 1.0f);
}

// async global->LDS, 16B per lane. LDS dest is wave-uniform base + lane*16.
__device__ __forceinline__ void gload16(const void* g, void* l) {
    __builtin_amdgcn_global_load_lds(
        (const __attribute__((address_space(1))) void*)g,
        (__attribute__((address_space(3))) void*)l, 16, 0, 0);
}

// counted wait + barrier: keep deeper tiles' loads in flight across it.
#define WAITB(N) asm volatile("s_waitcnt vmcnt(" #N ")\n\ts_barrier" ::: "memory")

// Chunk-XOR swizzled address for element (row, k) in a [*, L] bf16 matrix:
// within each 64-col K-tile, 16B chunk slot = ((k>>3)&7) ^ (row&7).
__device__ __forceinline__ int swz_ad(int row, int k, int L) {
    return row * L + (k & ~63) + ((((k >> 3) & 7) ^ (row & 7)) << 3) + (k & 7);
}

// ---------------------------------------------------------------------------
// Kernel 0 (prep): one memory-bound pass producing all bf16 operands.
//   abf16[8192][1152] = bf16([x | io | cf])             (chunk-XOR swizzled)
//   wfrag             = 0.5*[Wi2io | Wio2io+I | Wcf2io] in FRAG order:
//       element (n,k): kt=k>>6, ks=(k>>5)&1, c16=n>>4,
//       lane l=(n&15)|(((k>>3)&3)<<4), elem e=k&7;
//       addr = ((((kt<<5)|c16)<<1)|ks)*512 + l*8 + e.
//   w2s [128][512]    = Wio2o                            (chunk-XOR swizzled)
//   bsum[512]         = 0.5*(bi2io + bio2io + bcf2io)
// ---------------------------------------------------------------------------
__global__ __launch_bounds__(256) void k_prep(
    const float* __restrict__ x, const float* __restrict__ io,
    const float* __restrict__ cf,
    const float* __restrict__ Wi2io, const float* __restrict__ Wio2io,
    const float* __restrict__ Wcf2io, const float* __restrict__ Wio2o,
    const float* __restrict__ b1, const float* __restrict__ b2,
    const float* __restrict__ b3,
    unsigned short* __restrict__ abf16, unsigned short* __restrict__ wfrag,
    unsigned short* __restrict__ w2s, float* __restrict__ bsum)
{
    int idx = blockIdx.x * 256 + threadIdx.x;
    if (idx < 1179648) {                 // A: 8192 rows x 144 chunks
        int m = idx / 144;
        int k = (idx - m * 144) * 8;
        const float* s;
        if (k < 128)      s = x  + m * 128 + k;
        else if (k < 640) s = io + m * 512 + (k - 128);
        else              s = cf + m * 512 + (k - 640);
        f32x4 v0 = *(const f32x4*)s;
        f32x4 v1 = *(const f32x4*)(s + 4);
        bf16x4 h0 = __builtin_convertvector(v0, bf16x4);
        bf16x4 h1 = __builtin_convertvector(v1, bf16x4);
        *(bf16x8*)(abf16 + swz_ad(m, k, 1152)) =
            __builtin_shufflevector(h0, h1, 0,1,2,3,4,5,6,7);
    } else if (idx < 1253376) {          // wfrag: 512 rows x 144 chunks
        int q = idx - 1179648;
        int n = q / 144;
        int k = (q - n * 144) * 8;
        const float* s;
        if (k < 128)      s = Wi2io  + n * 128 + k;
        else if (k < 640) s = Wio2io + n * 512 + (k - 128);
        else              s = Wcf2io + n * 512 + (k - 640);
        f32x4 v0 = *(const f32x4*)s;
        f32x4 v1 = *(const f32x4*)(s + 4);
        float w[8];
        #pragma unroll
        for (int t = 0; t < 4; ++t) { w[t] = 0.5f * v0[t]; w[t+4] = 0.5f * v1[t]; }
        #pragma unroll
        for (int t = 0; t < 8; ++t) {
            int kk = k + t;
            if (kk >= 128 && kk < 640 && (kk - 128) == n) w[t] += 0.5f;  // +0.5*I
        }
        int kt = k >> 6, ks = (k >> 5) & 1, c16 = n >> 4;
        int l = (n & 15) | (((k >> 3) & 3) << 4);
        unsigned short* dst = wfrag + ((((kt << 5) | c16) << 1) | ks) * 512 + l * 8;
        #pragma unroll
        for (int t = 0; t < 8; ++t) dst[t] = f2bf(w[t]);
    } else if (idx < 1261568) {          // w2s: 128 rows x 64 chunks
        int q = idx - 1253376;
        int n = q >> 6;
        int k = (q & 63) * 8;
        f32x4 v0 = *(const f32x4*)(Wio2o + n * 512 + k);
        f32x4 v1 = *(const f32x4*)(Wio2o + n * 512 + k + 4);
        bf16x4 h0 = __builtin_convertvector(v0, bf16x4);
        bf16x4 h1 = __builtin_convertvector(v1, bf16x4);
        *(bf16x8*)(w2s + swz_ad(n, k, 512)) =
            __builtin_shufflevector(h0, h1, 0,1,2,3,4,5,6,7);
    } else if (idx < 1262080) {
        int n = idx - 1261568;
        bsum[n] = 0.5f * (b1[n] + b2[n] + b3[n]);
    }
}

// ---------------------------------------------------------------------------
// Kernel 1: ionew = tanh(abf16 @ wcat^T + bsum), bf16 out (stored swizzled).
// M=8192 N=512 K=1152. BM=128 BN=128 BK=64, 512 thr (8 waves 4m x 2n, wave
// 32x64). Grid 256 = 1 block/CU, XCD-affine (8 panels x 4 colb per XCD).
// LDS 3 x 16KB (A only). A: gl_lds 2 tiles ahead, WAITB(2) steady-state.
// B: direct frag loads from wfrag (1KB coalesced per frag, L1-resident).
// ---------------------------------------------------------------------------
__global__ __launch_bounds__(512, 2) void k_gemm1(
    const unsigned short* __restrict__ abf16,
    const unsigned short* __restrict__ wfrag,
    const float* __restrict__ bsum,
    unsigned short* __restrict__ ionew)
{
    __shared__ __align__(16) char lds[3][16384];   // A only

    const int tid = threadIdx.x, b = blockIdx.x;
    const int xcd = b & 7, idx = b >> 3;           // idx 0..31
    const int m0 = ((xcd << 3) | (idx & 7)) << 7;  // panel*128
    const int n0 = (idx >> 3) << 7;                // colb*128

    const int lane = tid & 63, wid = tid >> 6;
    const int li = lane & 15, lh = lane >> 4;
    const int wm = (wid >> 1) << 5;       // 0/32/64/96
    const int wn = (wid & 1) << 6;        // 0/64

    // A staging offsets (global pre-swizzled -> linear gl_lds).
    int a_off[2];
    #pragma unroll
    for (int j = 0; j < 2; ++j) {
        int ra = (wid << 4) + (j << 3) + (lane >> 3);    // A row 0..127
        a_off[j] = (m0 + ra) * 1152 + ((lane & 7) << 3);
    }
    const int adst = wid << 11;          // + j<<10

    // B frag base: frag addr = fb + kt*32768 + nj*1024 + ks*512 (elements).
    const unsigned short* fb = wfrag + ((n0 + wn) >> 4) * 1024 + lane * 8;

    f32x4 zz = {0.f, 0.f, 0.f, 0.f};
    f32x4 acc[2][4];
    #pragma unroll
    for (int i = 0; i < 2; ++i)
        #pragma unroll
        for (int j = 0; j < 4; ++j) acc[i][j] = zz;
    bf16x8 Bv[4][2];                     // [nj][ks], static-indexed (unrolled)

#define ASTAGE(KT, BUF) do {                                                   \
        char* A_ = (BUF);                                                      \
        const unsigned short* ap = abf16 + ((KT) << 6);                        \
        gload16(ap + a_off[0], A_ + adst);                                     \
        gload16(ap + a_off[1], A_ + adst + 1024);                              \
    } while (0)

#define BLOAD(KT) do {                                                         \
        const unsigned short* fp = fb + (size_t)(KT) * 32768;                  \
        _Pragma("unroll")                                                      \
        for (int nj = 0; nj < 4; ++nj)                                         \
            _Pragma("unroll")                                                  \
            for (int ks = 0; ks < 2; ++ks)                                     \
                Bv[nj][ks] = *(const bf16x8*)(fp + nj * 1024 + ks * 512);      \
    } while (0)

#define COMPUTE1(BUF) do {                                                     \
        const char* A_ = (BUF);                                                \
        _Pragma("unroll")                                                      \
        for (int ks = 0; ks < 2; ++ks) {                                       \
            int c = ks * 4 + lh;                                               \
            bf16x8 af[2];                                                      \
            _Pragma("unroll")                                                  \
            for (int mi = 0; mi < 2; ++mi) {                                   \
                int r = wm + mi * 16 + li;                                     \
                af[mi] = *(const bf16x8*)(A_ + r * 128 + ((c ^ (r & 7)) << 4));\
            }                                                                  \
            __builtin_amdgcn_s_setprio(1);                                     \
            _Pragma("unroll")                                                  \
            for (int nj = 0; nj < 4; ++nj) {                                   \
                acc[0][nj] = __builtin_amdgcn_mfma_f32_16x16x32_bf16(          \
                    af[0], Bv[nj][ks], acc[0][nj], 0, 0, 0);                   \
                acc[1][nj] = __builtin_amdgcn_mfma_f32_16x16x32_bf16(          \
                    af[1], Bv[nj][ks], acc[1][nj], 0, 0, 0);                   \
            }                                                                  \
            __builtin_amdgcn_s_setprio(0);                                     \
        }                                                                      \
    } while (0)

    ASTAGE(0, lds[0]);
    ASTAGE(1, lds[1]);
    char* p0 = lds[0]; char* p1 = lds[1]; char* p2 = lds[2];
    #pragma unroll 1
    for (int t = 0; t < 18; ++t) {
        if (t < 17) { WAITB(2); } else { WAITB(0); }
        BLOAD(t);                            // L1/L2 frag loads, retire at use
        if (t + 2 < 18) ASTAGE(t + 2, p2);   // A 2 tiles ahead
        COMPUTE1(p0);
        char* tmp = p0; p0 = p1; p1 = p2; p2 = tmp;
    }
#undef ASTAGE
#undef BLOAD
#undef COMPUTE1

    // epilogue: bias+tanh, store bf16 chunk-swizzled (gemm2-ready layout)
    #pragma unroll
    for (int nj = 0; nj < 4; ++nj) {
        int gn = n0 + wn + nj * 16 + li;
        float bb = bsum[gn];
        #pragma unroll
        for (int mi = 0; mi < 2; ++mi) {
            #pragma unroll
            for (int r = 0; r < 4; ++r) {
                int gm = m0 + wm + mi * 16 + (lh << 2) + r;
                float v = tanh_fast(acc[mi][nj][r] + bb);
                ionew[swz_ad(gm, gn, 512)] = f2bf(v);
            }
        }
    }
}

// ---------------------------------------------------------------------------
// Kernel 2: y = tanh(ionew @ w2s^T + bio2o). M=8192 N=128 K=512.
// BM=32 BN=128(full) BK=64, 256 thr (4 waves, wave 32x32). Grid 256.
// 3-buffer counted pipeline (5 gl_lds/stage -> WAITB(5)). [r8, unchanged]
// ---------------------------------------------------------------------------
__global__ __launch_bounds__(256, 2) void k_gemm2(
    const unsigned short* __restrict__ ionew,
    const unsigned short* __restrict__ w2s,
    const float* __restrict__ b4,
    float* __restrict__ out)
{
    __shared__ __align__(16) char lds[3][20480];   // A @0 (4KB), B @4096 (16KB)

    const int tid = threadIdx.x, b = blockIdx.x;
    const int xcd = b & 7, idx = b >> 3;           // idx 0..31
    const int m0 = ((xcd << 5) | idx) << 5;        // matches gemm1 writer XCD

    const int lane = tid & 63, wid = tid >> 6;
    const int li = lane & 15, lh = lane >> 4;
    const int wn = wid << 5;                       // 32 out-cols per wave

    const int a2_off = (m0 + (wid << 3) + (lane >> 3)) * 512 + ((lane & 7) << 3);
    int b2_off[4];
    #pragma unroll
    for (int j = 0; j < 4; ++j)
        b2_off[j] = ((wid << 5) + 8 * j + (lane >> 3)) * 512 + ((lane & 7) << 3);

    f32x4 zz = {0.f, 0.f, 0.f, 0.f};
    f32x4 acc[2][2];
    acc[0][0] = zz; acc[0][1] = zz; acc[1][0] = zz; acc[1][1] = zz;

#define STAGE2(KT, BUF) do {                                                   \
        int K_ = (KT);                                                         \
        char* A_ = (BUF); char* B_ = (BUF) + 4096;                             \
        gload16(ionew + a2_off + (K_ << 6), A_ + (wid << 10));                 \
        _Pragma("unroll")                                                      \
        for (int j = 0; j < 4; ++j)                                            \
            gload16(w2s + b2_off[j] + (K_ << 6), B_ + (wid << 12) + j * 1024); \
    } while (0)

#define COMPUTE2(BUF) do {                                                     \
        const char* A_ = (BUF); const char* B_ = (BUF) + 4096;                 \
        _Pragma("unroll")                                                      \
        for (int ks = 0; ks < 2; ++ks) {                                       \
            int c = ks * 4 + lh;                                               \
            bf16x8 av[2];                                                      \
            _Pragma("unroll")                                                  \
            for (int mi = 0; mi < 2; ++mi) {                                   \
                int r = mi * 16 + li;                                          \
                av[mi] = *(const bf16x8*)(A_ + r * 128 + ((c ^ (r & 7)) << 4));\
            }                                                                  \
            _Pragma("unroll")                                                  \
            for (int nj = 0; nj < 2; ++nj) {                                   \
                int rb = wn + nj * 16 + li;                                    \
                bf16x8 bv = *(const bf16x8*)(B_ + rb * 128 +                   \
                                             ((c ^ (rb & 7)) << 4));           \
                acc[0][nj] = __builtin_amdgcn_mfma_f32_16x16x32_bf16(          \
                    av[0], bv, acc[0][nj], 0, 0, 0);                           \
                acc[1][nj] = __builtin_amdgcn_mfma_f32_16x16x32_bf16(          \
                    av[1], bv, acc[1][nj], 0, 0, 0);                           \
            }                                                                  \
        }                                                                      \
    } while (0)

    STAGE2(0, lds[0]);
    STAGE2(1, lds[1]);
    char* p0 = lds[0]; char* p1 = lds[1]; char* p2 = lds[2];
    #pragma unroll 1
    for (int t = 0; t < 7; ++t) {
        WAITB(5);
        if (t + 2 < 8) STAGE2(t + 2, p2);
        COMPUTE2(p0);
        char* tmp = p0; p0 = p1; p1 = p2; p2 = tmp;
    }
    WAITB(0);
    COMPUTE2(p0);                          // tile 7
#undef STAGE2
#undef COMPUTE2

    #pragma unroll
    for (int nj = 0; nj < 2; ++nj) {
        int n = wn + nj * 16 + li;
        float bb = b4[n];
        #pragma unroll
        for (int mi = 0; mi < 2; ++mi) {
            #pragma unroll
            for (int r = 0; r < 4; ++r) {
                int gm = m0 + mi * 16 + (lh << 2) + r;
                out[(size_t)gm * 128 + n] = tanh_fast(acc[mi][nj][r] + bb);
            }
        }
    }
}

// ---------------------------------------------------------------------------
extern "C" void kernel_launch(void* const* d_in, const int* in_sizes, int n_in,
                              void* d_out, int out_size, void* d_ws, size_t ws_size,
                              hipStream_t stream)
{
    const float* x      = (const float*)d_in[0];
    const float* io     = (const float*)d_in[1];
    const float* cf     = (const float*)d_in[2];
    // d_in[3] cs_state: dead (does not feed y)
    const float* Wi2io  = (const float*)d_in[4];
    const float* bi2io  = (const float*)d_in[5];
    const float* Wio2o  = (const float*)d_in[6];
    const float* bio2o  = (const float*)d_in[7];
    const float* Wio2io = (const float*)d_in[8];
    const float* bio2io = (const float*)d_in[9];
    const float* Wcf2io = (const float*)d_in[12];
    const float* bcf2io = (const float*)d_in[13];
    float* out = (float*)d_out;

    // ws: abf16 18,874,368 | wfrag 1,179,648 | w2s 131,072 | bsum 2,048
    //   | ionew 8,388,608   (total ~28.6 MB)
    char* ws = (char*)d_ws;
    unsigned short* abf16 = (unsigned short*)ws;
    unsigned short* wfrag = (unsigned short*)(ws + 18874368);
    unsigned short* w2s   = (unsigned short*)(ws + 20054016);
    float*          bsum  = (float*)(ws + 20185088);
    unsigned short* ionew = (unsigned short*)(ws + 20187136);

    hipLaunchKernelGGL(k_prep, dim3(4930), dim3(256), 0, stream,
                       x, io, cf, Wi2io, Wio2io, Wcf2io, Wio2o,
                       bi2io, bio2io, bcf2io, abf16, wfrag, w2s, bsum);
    hipLaunchKernelGGL(k_gemm1, dim3(256), dim3(512), 0, stream,
                       abf16, wfrag, bsum, ionew);
    hipLaunchKernelGGL(k_gemm2, dim3(256), dim3(256), 0, stream,
                       ionew, w2s, bio2o, out);
}

// Round 13
// 35.827 us; speedup vs baseline: 1.1806x; 1.1806x over previous
//
#include <hip/hip_runtime.h>

// MTRNN single step, fused. Live computation (reference returns only y):
//   io_new = tanh([x|io|cf] @ (0.5*[Wi2io | Wio2io+I | Wcf2io])^T + bsum)
//   y      = tanh(io_new @ Wio2o^T + bio2o)
// One block = 32 batch rows x ALL 512 io cols -> io_new stays in LDS and
// gemm2 runs in-block (no ionew HBM round-trip, no 3rd kernel, no A prepass).
// All staging via global_load_lds with counted vmcnt (r8's proven pattern):
// phase 1: A f32 (1 gl_lds/wave) + B bf16 (8 gl_lds/wave) per K-tile,
// 2 buffers, 2 tiles in flight, steady-state vmcnt(9).
// phase 2: w2s 2-buffer gl_lds, vmcnt(2).

typedef float f32x4 __attribute__((ext_vector_type(4)));
typedef __bf16 bf16x4 __attribute__((ext_vector_type(4)));
typedef __bf16 bf16x8 __attribute__((ext_vector_type(8)));
typedef unsigned short u16x4 __attribute__((ext_vector_type(4)));

__device__ __forceinline__ unsigned short f2bf(float f) {
    unsigned u = __builtin_bit_cast(unsigned, f);
    u += 0x7FFFu + ((u >> 16) & 1u);
    return (unsigned short)(u >> 16);
}

__device__ __forceinline__ float tanh_fast(float x) {
    float e = __expf(2.0f * x);
    return 1.0f - 2.0f * __builtin_amdgcn_rcpf(e + 1.0f);
}

// async global->LDS, 16B per lane. LDS dest is wave-uniform base + lane*16.
__device__ __forceinline__ void gload16(const void* g, void* l) {
    __builtin_amdgcn_global_load_lds(
        (const __attribute__((address_space(1))) void*)g,
        (__attribute__((address_space(3))) void*)l, 16, 0, 0);
}

// counted wait + barrier (lgkm publishes ds ops; vmcnt keeps newer loads flying)
#define WAITB(N) asm volatile("s_waitcnt vmcnt(" #N ") lgkmcnt(0)\n\ts_barrier" ::: "memory")
#define BARL()   asm volatile("s_waitcnt lgkmcnt(0)\n\ts_barrier" ::: "memory")

// ---------------------------------------------------------------------------
// Kernel 0: pack weights to bf16, CHUNK-XOR swizzled per 64-col K-tile:
// element (n,k) -> n*L + (k&~63) + ((((k>>3)&7) ^ (n&7))<<3) + (k&7).
//   wcat[512][1152] = 0.5*[Wi2io | Wio2io + I | Wcf2io]
//   w2s [128][512]  = Wio2o
//   bsum[512]       = 0.5*(bi2io + bio2io + bcf2io)
// ---------------------------------------------------------------------------
__global__ __launch_bounds__(256) void k_convert(
    const float* __restrict__ Wi2io, const float* __restrict__ Wio2io,
    const float* __restrict__ Wcf2io, const float* __restrict__ Wio2o,
    const float* __restrict__ b1, const float* __restrict__ b2,
    const float* __restrict__ b3,
    unsigned short* __restrict__ wcat, unsigned short* __restrict__ w2s,
    float* __restrict__ bsum)
{
    int idx = blockIdx.x * 256 + threadIdx.x;
    if (idx < 147456) {              // 512*1152/4 quads
        int n = idx / 288;
        int k = (idx - n * 288) * 4;
        const float* s;
        if (k < 128)      s = Wi2io  + n * 128 + k;
        else if (k < 640) s = Wio2io + n * 512 + (k - 128);
        else              s = Wcf2io + n * 512 + (k - 640);
        f32x4 v = *(const f32x4*)s;
        u16x4 h;
        #pragma unroll
        for (int t = 0; t < 4; ++t) {
            float f = 0.5f * v[t];
            int kk = k + t;
            if (kk >= 128 && kk < 640 && (kk - 128) == n) f += 0.5f;  // +0.5*I
            h[t] = f2bf(f);
        }
        int ad = n * 1152 + (k & ~63) + ((((k >> 3) & 7) ^ (n & 7)) << 3) + (k & 7);
        *(u16x4*)(wcat + ad) = h;
    } else if (idx < 163840) {       // 128*512/4 quads
        int q = idx - 147456;
        int n = q >> 7;
        int k = (q & 127) * 4;
        f32x4 v = *(const f32x4*)(Wio2o + n * 512 + k);
        u16x4 h; h[0]=f2bf(v[0]); h[1]=f2bf(v[1]); h[2]=f2bf(v[2]); h[3]=f2bf(v[3]);
        int ad = n * 512 + (k & ~63) + ((((k >> 3) & 7) ^ (n & 7)) << 3) + (k & 7);
        *(u16x4*)(w2s + ad) = h;
    } else if (idx < 164352) {
        int n = idx - 163840;
        bsum[n] = 0.5f * (b1[n] + b2[n] + b3[n]);
    }
}

// ---------------------------------------------------------------------------
// Fused kernel. Grid 256 x 512 thr (8 waves). Block = batch rows [32b, 32b+32).
// LDS map (147456 B total): buffers B0 @0, B1 @73728; each = A f32 8KB @+0,
// B bf16 64KB @+8192. Phase 2 reuses B0 region: io_new 32KB @0,
// w2 buffers W0 @36864, W1 @53248 (16KB each).
// ---------------------------------------------------------------------------
__global__ __launch_bounds__(512) void k_fused(
    const float* __restrict__ x, const float* __restrict__ io,
    const float* __restrict__ cf,
    const unsigned short* __restrict__ wcat,
    const unsigned short* __restrict__ w2s,
    const float* __restrict__ bsum, const float* __restrict__ b4,
    float* __restrict__ out)
{
    __shared__ __align__(16) char lds[147456];

    const int tid = threadIdx.x;
    const int m0  = blockIdx.x << 5;
    const int lane = tid & 63, wid = tid >> 6;
    const int li = lane & 15, lh = lane >> 4;

    // ---- phase-1 staging offsets ----
    // A: wave w stages rows [4w,4w+4): lane -> row 4w+(l>>4), chunk (l&15)^(row&15)
    const int arow = (wid << 2) + (lane >> 4);
    const int acs  = (lane & 15) ^ (arow & 15);
    const size_t a_x = (size_t)(m0 + arow) * 128 + acs * 4;
    const size_t a_s = (size_t)(m0 + arow) * 512 + acs * 4;
    // B: wave w stages rows [64w, 64w+64) in 8 groups of 8 rows
    int b_src[8];
    #pragma unroll
    for (int j = 0; j < 8; ++j) {
        int rb = (wid << 6) + (j << 3) + (lane >> 3);
        b_src[j] = rb * 1152 + ((lane & 7) << 3);     // pre-swizzled global
    }
    // phase-2 w2 staging: wave w stages rows [16w, 16w+16) in 2 groups
    int w_src[2];
    #pragma unroll
    for (int j = 0; j < 2; ++j)
        w_src[j] = ((wid << 4) + (j << 3) + (lane >> 3)) * 512 + ((lane & 7) << 3);

    f32x4 zz = {0.f, 0.f, 0.f, 0.f};
    f32x4 acc[2][4];
    #pragma unroll
    for (int i = 0; i < 2; ++i)
        #pragma unroll
        for (int j = 0; j < 4; ++j) acc[i][j] = zz;

#define STAGE1(KT, BASE) do {                                                  \
        int K_ = (KT);                                                         \
        if (K_ < 2)       gload16(x  + (K_ << 6) + a_x,                        \
                                  lds + (BASE) + (wid << 10));                 \
        else if (K_ < 10) gload16(io + ((K_ - 2) << 6) + a_s,                  \
                                  lds + (BASE) + (wid << 10));                 \
        else              gload16(cf + ((K_ - 10) << 6) + a_s,                 \
                                  lds + (BASE) + (wid << 10));                 \
        const unsigned short* wp = wcat + (K_ << 6);                           \
        _Pragma("unroll")                                                      \
        for (int j = 0; j < 8; ++j)                                            \
            gload16(wp + b_src[j],                                             \
                    lds + (BASE) + 8192 + (wid << 13) + (j << 10));            \
    } while (0)

#define COMPUTE1(BASE) do {                                                    \
        const char* A_ = lds + (BASE);                                         \
        const char* Bb = lds + (BASE) + 8192;                                  \
        _Pragma("unroll")                                                      \
        for (int ks = 0; ks < 2; ++ks) {                                       \
            int c0 = ks * 8 + lh * 2;                                          \
            bf16x8 af[2];                                                      \
            _Pragma("unroll")                                                  \
            for (int mi = 0; mi < 2; ++mi) {                                   \
                int r = mi * 16 + li;                                          \
                f32x4 a0 = *(const f32x4*)(A_ + r * 256 +                      \
                                           ((c0 ^ (r & 15)) << 4));            \
                f32x4 a1 = *(const f32x4*)(A_ + r * 256 +                      \
                                           (((c0 + 1) ^ (r & 15)) << 4));      \
                bf16x4 h0 = __builtin_convertvector(a0, bf16x4);               \
                bf16x4 h1 = __builtin_convertvector(a1, bf16x4);               \
                af[mi] = __builtin_shufflevector(h0, h1, 0,1,2,3,4,5,6,7);     \
            }                                                                  \
            int c = ks * 4 + lh;                                               \
            _Pragma("unroll")                                                  \
            for (int nj = 0; nj < 4; ++nj) {                                   \
                int rb = (wid << 6) + nj * 16 + li;                            \
                bf16x8 bv = *(const bf16x8*)(Bb + rb * 128 +                   \
                                             ((c ^ (rb & 7)) << 4));           \
                acc[0][nj] = __builtin_amdgcn_mfma_f32_16x16x32_bf16(          \
                    af[0], bv, acc[0][nj], 0, 0, 0);                           \
                acc[1][nj] = __builtin_amdgcn_mfma_f32_16x16x32_bf16(          \
                    af[1], bv, acc[1][nj], 0, 0, 0);                           \
            }                                                                  \
        }                                                                      \
    } while (0)

#define W2STAGE(KT, WBASE) do {                                                \
        const unsigned short* wp2 = w2s + ((KT) << 6);                         \
        gload16(wp2 + w_src[0], lds + (WBASE) + (wid << 11));                  \
        gload16(wp2 + w_src[1], lds + (WBASE) + (wid << 11) + 1024);           \
    } while (0)

    // ---- phase 1: 18 K-tiles, 2 buffers, loads 2 tiles in flight ----
    STAGE1(0, 0);
    STAGE1(1, 73728);
    #pragma unroll 1
    for (int t = 0; t < 17; ++t) {
        WAITB(9);                            // tile t retired; t+1 in flight
        int cb = (t & 1) ? 73728 : 0;
        COMPUTE1(cb);
        BARL();                              // all reads done before overwrite
        if (t + 2 < 18) STAGE1(t + 2, cb);
    }
    WAITB(0);
    W2STAGE(0, 36864);                       // prefetch phase-2 weights early
    W2STAGE(1, 53248);
    COMPUTE1(73728);                         // tile 17 (buffer B1)

    // ---- handoff: io_new = tanh(acc + bsum) -> bf16 -> LDS @0 (swizzled) ----
    {
        unsigned short* IO16 = (unsigned short*)lds;
        #pragma unroll
        for (int nj = 0; nj < 4; ++nj) {
            int gn = (wid << 6) + nj * 16 + li;
            float bb = bsum[gn];
            #pragma unroll
            for (int mi = 0; mi < 2; ++mi) {
                #pragma unroll
                for (int r = 0; r < 4; ++r) {
                    int m = mi * 16 + (lh << 2) + r;
                    float v = tanh_fast(acc[mi][nj][r] + bb);
                    int ad = m * 512 + (gn & ~63) +
                             ((((gn >> 3) & 7) ^ (m & 7)) << 3) + (gn & 7);
                    IO16[ad] = f2bf(v);
                }
            }
        }
    }

    // ---- phase 2: y = tanh(io_new @ w2^T + b4), 8 K-tiles of 64 ----
    f32x4 acc2[2];
    acc2[0] = zz; acc2[1] = zz;

#define COMPUTE2(KT, WBASE) do {                                               \
        _Pragma("unroll")                                                      \
        for (int ks = 0; ks < 2; ++ks) {                                       \
            int c = ks * 4 + lh;                                               \
            bf16x8 af2[2];                                                     \
            _Pragma("unroll")                                                  \
            for (int mi = 0; mi < 2; ++mi) {                                   \
                int m = mi * 16 + li;                                          \
                af2[mi] = *(const bf16x8*)(lds + m * 1024 + ((KT) << 7) +      \
                                           ((c ^ (m & 7)) << 4));              \
            }                                                                  \
            int rb = (wid << 4) + li;                                          \
            bf16x8 bv = *(const bf16x8*)(lds + (WBASE) + rb * 128 +            \
                                         ((c ^ (rb & 7)) << 4));               \
            acc2[0] = __builtin_amdgcn_mfma_f32_16x16x32_bf16(                 \
                af2[0], bv, acc2[0], 0, 0, 0);                                 \
            acc2[1] = __builtin_amdgcn_mfma_f32_16x16x32_bf16(                 \
                af2[1], bv, acc2[1], 0, 0, 0);                                 \
        }                                                                      \
    } while (0)

    #pragma unroll 1
    for (int t2 = 0; t2 < 7; ++t2) {
        WAITB(2);                            // w2 tile t2 retired; t2+1 flying
        int wb = (t2 & 1) ? 53248 : 36864;
        COMPUTE2(t2, wb);
        BARL();
        if (t2 + 2 < 8) W2STAGE(t2 + 2, wb);
    }
    WAITB(0);
    COMPUTE2(7, 53248);

    // ---- epilogue: out[m0+m][n] ----
    {
        int n = (wid << 4) + li;
        float bb = b4[n];
        #pragma unroll
        for (int mi = 0; mi < 2; ++mi) {
            #pragma unroll
            for (int r = 0; r < 4; ++r) {
                int m = mi * 16 + (lh << 2) + r;
                out[(size_t)(m0 + m) * 128 + n] = tanh_fast(acc2[mi][r] + bb);
            }
        }
    }
#undef STAGE1
#undef COMPUTE1
#undef W2STAGE
#undef COMPUTE2
}

// ---------------------------------------------------------------------------
extern "C" void kernel_launch(void* const* d_in, const int* in_sizes, int n_in,
                              void* d_out, int out_size, void* d_ws, size_t ws_size,
                              hipStream_t stream)
{
    const float* x      = (const float*)d_in[0];
    const float* io     = (const float*)d_in[1];
    const float* cf     = (const float*)d_in[2];
    // d_in[3] cs_state: dead (does not feed y)
    const float* Wi2io  = (const float*)d_in[4];
    const float* bi2io  = (const float*)d_in[5];
    const float* Wio2o  = (const float*)d_in[6];
    const float* bio2o  = (const float*)d_in[7];
    const float* Wio2io = (const float*)d_in[8];
    const float* bio2io = (const float*)d_in[9];
    const float* Wcf2io = (const float*)d_in[12];
    const float* bcf2io = (const float*)d_in[13];
    float* out = (float*)d_out;

    // ws: wcat 1,179,648 | w2s 131,072 | bsum 2,048
    char* ws = (char*)d_ws;
    unsigned short* wcat = (unsigned short*)ws;
    unsigned short* w2s  = (unsigned short*)(ws + 1179648);
    float*          bsum = (float*)(ws + 1310720);

    hipLaunchKernelGGL(k_convert, dim3(642), dim3(256), 0, stream,
                       Wi2io, Wio2io, Wcf2io, Wio2o, bi2io, bio2io, bcf2io,
                       wcat, w2s, bsum);
    hipLaunchKernelGGL(k_fused, dim3(256), dim3(512), 0, stream,
                       x, io, cf, wcat, w2s, bsum, bio2o, out);
}

// Round 14
// 33.388 us; speedup vs baseline: 1.2668x; 1.0730x over previous
//
#include <hip/hip_runtime.h>

// MTRNN single step. Live computation after DCE (reference returns only y):
//   io_new = tanh([x|io|cf] @ (0.5*[Wi2io | Wio2io+I | Wcf2io])^T + bsum)
//   y      = tanh(io_new @ Wio2o^T + bio2o)
// cf_new / cs_new dead. bf16 MFMA, f32 accumulate.
// r14 = r8's counted-vmcnt gl_lds staging at 2 blocks/CU:
//  gemm1: BM=64 BN=128, 256 thr, grid 512, 2-buffer counted (WAITB(8)+BARL).
//  gemm2: BM=32 BN=64, 128 thr, grid 512, 3-buffer counted (WAITB(6)).

typedef float f32x4 __attribute__((ext_vector_type(4)));
typedef __bf16 bf16x4 __attribute__((ext_vector_type(4)));
typedef __bf16 bf16x8 __attribute__((ext_vector_type(8)));
typedef unsigned short u16x4 __attribute__((ext_vector_type(4)));

__device__ __forceinline__ unsigned short f2bf(float f) {
    unsigned u = __builtin_bit_cast(unsigned, f);
    u += 0x7FFFu + ((u >> 16) & 1u);
    return (unsigned short)(u >> 16);
}

__device__ __forceinline__ float tanh_fast(float x) {
    float e = __expf(2.0f * x);
    return 1.0f - 2.0f * __builtin_amdgcn_rcpf(e + 1.0f);
}

// async global->LDS, 16B per lane. LDS dest is wave-uniform base + lane*16.
__device__ __forceinline__ void gload16(const void* g, void* l) {
    __builtin_amdgcn_global_load_lds(
        (const __attribute__((address_space(1))) void*)g,
        (__attribute__((address_space(3))) void*)l, 16, 0, 0);
}

// counted wait + barrier: keep newer stages' loads in flight across it.
#define WAITB(N) asm volatile("s_waitcnt vmcnt(" #N ")\n\ts_barrier" ::: "memory")
// plain barrier (guards LDS overwrite after all waves finished reading).
#define BARL()   asm volatile("s_waitcnt lgkmcnt(0)\n\ts_barrier" ::: "memory")

// ---------------------------------------------------------------------------
// Kernel 0: pack weights to bf16, CHUNK-XOR swizzled per 64-col K-tile:
// element (n,k) -> n*L + (k&~63) + ((((k>>3)&7) ^ (n&7))<<3) + (k&7).
//   wcat[512][1152] = 0.5*[Wi2io | Wio2io + I | Wcf2io]
//   w2s [128][512]  = Wio2o
//   bsum[512]       = 0.5*(bi2io + bio2io + bcf2io)
// ---------------------------------------------------------------------------
__global__ __launch_bounds__(256) void k_convert(
    const float* __restrict__ Wi2io, const float* __restrict__ Wio2io,
    const float* __restrict__ Wcf2io, const float* __restrict__ Wio2o,
    const float* __restrict__ b1, const float* __restrict__ b2,
    const float* __restrict__ b3,
    unsigned short* __restrict__ wcat, unsigned short* __restrict__ w2s,
    float* __restrict__ bsum)
{
    int idx = blockIdx.x * 256 + threadIdx.x;
    if (idx < 147456) {              // 512*1152/4 quads
        int n = idx / 288;
        int k = (idx - n * 288) * 4;
        const float* s;
        if (k < 128)      s = Wi2io  + n * 128 + k;
        else if (k < 640) s = Wio2io + n * 512 + (k - 128);
        else              s = Wcf2io + n * 512 + (k - 640);
        f32x4 v = *(const f32x4*)s;
        u16x4 h;
        #pragma unroll
        for (int t = 0; t < 4; ++t) {
            float f = 0.5f * v[t];
            int kk = k + t;
            if (kk >= 128 && kk < 640 && (kk - 128) == n) f += 0.5f;  // +0.5*I
            h[t] = f2bf(f);
        }
        int ad = n * 1152 + (k & ~63) + ((((k >> 3) & 7) ^ (n & 7)) << 3) + (k & 7);
        *(u16x4*)(wcat + ad) = h;
    } else if (idx < 163840) {       // 128*512/4 quads
        int q = idx - 147456;
        int n = q >> 7;
        int k = (q & 127) * 4;
        f32x4 v = *(const f32x4*)(Wio2o + n * 512 + k);
        u16x4 h; h[0]=f2bf(v[0]); h[1]=f2bf(v[1]); h[2]=f2bf(v[2]); h[3]=f2bf(v[3]);
        int ad = n * 512 + (k & ~63) + ((((k >> 3) & 7) ^ (n & 7)) << 3) + (k & 7);
        *(u16x4*)(w2s + ad) = h;
    } else if (idx < 164352) {
        int n = idx - 163840;
        bsum[n] = 0.5f * (b1[n] + b2[n] + b3[n]);
    }
}

// ---------------------------------------------------------------------------
// Kernel 1: ionew = tanh(Acat @ wcat^T + bsum), bf16 out (stored swizzled).
// M=8192 N=512 K=1152. BM=64 BN=128 BK=64, 256 thr (4 waves 2m x 2n, wave
// 32x64). Grid 512 = 2 blocks/CU. LDS 2 x (A f32 16KB | B bf16 16KB) = 64KB.
// 2-buffer counted pipeline: WAITB(8) retires tile t, tile t+1 stays in
// flight; BARL guards the buffer overwrite. XCD-affine (16 panels x 4 colb).
// ---------------------------------------------------------------------------
__global__ __launch_bounds__(256, 2) void k_gemm1(
    const float* __restrict__ x, const float* __restrict__ io,
    const float* __restrict__ cf,
    const unsigned short* __restrict__ wcat,
    const float* __restrict__ bsum,
    unsigned short* __restrict__ ionew)
{
    __shared__ __align__(16) char lds[2][32768];   // A @0 (16KB), B @16384

    const int tid = threadIdx.x, b = blockIdx.x;
    const int xcd = b & 7, idx = b >> 3;            // idx 0..63
    const int m0 = ((xcd << 4) | (idx & 15)) << 6;  // panel*64
    const int n0 = (idx >> 4) << 7;                 // colb*128

    const int lane = tid & 63, wid = tid >> 6;
    const int li = lane & 15, lh = lane >> 4;
    const int wm = (wid >> 1) << 5;       // 0/32
    const int wn = (wid & 1) << 6;        // 0/64

    // A staging: 64 rows x 16 chunks (f32, swizzle in source offset)
    int a_off_x[4], a_off_s[4], b_off[4];
    #pragma unroll
    for (int j = 0; j < 4; ++j) {
        int r = (wid << 4) + (j << 2) + (lane >> 4);     // A row 0..63
        int cs = (lane & 15) ^ (r & 15);                 // swizzled 16B chunk
        a_off_x[j] = (m0 + r) * 128 + cs * 4;
        a_off_s[j] = (m0 + r) * 512 + cs * 4;
        int rb = (wid << 5) + (j << 3) + (lane >> 3);    // B row 0..127
        b_off[j] = (n0 + rb) * 1152 + ((lane & 7) << 3); // linear (pre-swz)
    }
    const int adst = wid << 12;   // + j<<10 in each region

    f32x4 zz = {0.f, 0.f, 0.f, 0.f};
    f32x4 acc[2][4];
    #pragma unroll
    for (int i = 0; i < 2; ++i)
        #pragma unroll
        for (int j = 0; j < 4; ++j) acc[i][j] = zz;

#define STAGE1(KT, BUF) do {                                                   \
        int K_ = (KT);                                                         \
        char* A_ = (BUF); char* B_ = (BUF) + 16384;                            \
        if (K_ < 2) {                                                          \
            const float* sp = x + (K_ << 6);                                   \
            _Pragma("unroll")                                                  \
            for (int j = 0; j < 4; ++j)                                        \
                gload16(sp + a_off_x[j], A_ + adst + (j << 10));               \
        } else if (K_ < 10) {                                                  \
            const float* sp = io + ((K_ - 2) << 6);                            \
            _Pragma("unroll")                                                  \
            for (int j = 0; j < 4; ++j)                                        \
                gload16(sp + a_off_s[j], A_ + adst + (j << 10));               \
        } else {                                                               \
            const float* sp = cf + ((K_ - 10) << 6);                           \
            _Pragma("unroll")                                                  \
            for (int j = 0; j < 4; ++j)                                        \
                gload16(sp + a_off_s[j], A_ + adst + (j << 10));               \
        }                                                                      \
        const unsigned short* wp = wcat + (K_ << 6);                           \
        _Pragma("unroll")                                                      \
        for (int j = 0; j < 4; ++j)                                            \
            gload16(wp + b_off[j], B_ + adst + (j << 10));                     \
    } while (0)

#define COMPUTE1(BUF) do {                                                     \
        const char* A_ = (BUF); const char* B_ = (BUF) + 16384;                \
        _Pragma("unroll")                                                      \
        for (int ks = 0; ks < 2; ++ks) {                                       \
            bf16x8 af[2];                                                      \
            _Pragma("unroll")                                                  \
            for (int mi = 0; mi < 2; ++mi) {                                   \
                int r = wm + mi * 16 + li;                                     \
                int c0 = ks * 8 + lh * 2;                                      \
                f32x4 a0 = *(const f32x4*)(A_ + r * 256 +                      \
                                           ((c0 ^ (r & 15)) << 4));            \
                f32x4 a1 = *(const f32x4*)(A_ + r * 256 +                      \
                                           (((c0 + 1) ^ (r & 15)) << 4));      \
                bf16x4 h0 = __builtin_convertvector(a0, bf16x4);               \
                bf16x4 h1 = __builtin_convertvector(a1, bf16x4);               \
                af[mi] = __builtin_shufflevector(h0, h1, 0,1,2,3,4,5,6,7);     \
            }                                                                  \
            int c = ks * 4 + lh;                                               \
            _Pragma("unroll")                                                  \
            for (int nj = 0; nj < 4; ++nj) {                                   \
                int rb = wn + nj * 16 + li;                                    \
                bf16x8 bv = *(const bf16x8*)(B_ + rb * 128 +                   \
                                             ((c ^ (rb & 7)) << 4));           \
                acc[0][nj] = __builtin_amdgcn_mfma_f32_16x16x32_bf16(          \
                    af[0], bv, acc[0][nj], 0, 0, 0);                           \
                acc[1][nj] = __builtin_amdgcn_mfma_f32_16x16x32_bf16(          \
                    af[1], bv, acc[1][nj], 0, 0, 0);                           \
            }                                                                  \
        }                                                                      \
    } while (0)

    STAGE1(0, lds[0]);
    STAGE1(1, lds[1]);
    #pragma unroll 1
    for (int t = 0; t < 18; ++t) {
        if (t < 17) { WAITB(8); } else { WAITB(0); }   // tile t retired
        char* cb = lds[t & 1];
        COMPUTE1(cb);
        if (t + 2 < 18) {
            BARL();                                    // all reads of cb done
            STAGE1(t + 2, cb);
        }
    }
#undef STAGE1
#undef COMPUTE1

    // epilogue: bias+tanh, store bf16 chunk-swizzled (gemm2-ready layout)
    #pragma unroll
    for (int nj = 0; nj < 4; ++nj) {
        int gn = n0 + wn + nj * 16 + li;
        float bb = bsum[gn];
        #pragma unroll
        for (int mi = 0; mi < 2; ++mi) {
            #pragma unroll
            for (int r = 0; r < 4; ++r) {
                int gm = m0 + wm + mi * 16 + (lh << 2) + r;
                float v = tanh_fast(acc[mi][nj][r] + bb);
                int ad = gm * 512 + (gn & ~63) +
                         ((((gn >> 3) & 7) ^ (gm & 7)) << 3) + (gn & 7);
                ionew[ad] = f2bf(v);
            }
        }
    }
}

// ---------------------------------------------------------------------------
// Kernel 2: y = tanh(ionew @ w2s^T + bio2o). M=8192 N=128 K=512.
// BM=32 BN=64 BK=64, 128 thr (2 waves, wave 32x32). Grid 512 = 2+ blocks/CU.
// 3-buffer counted pipeline (6 gl_lds/wave/stage -> WAITB(6)).
// XCD map matches gemm1's ionew writers.
// ---------------------------------------------------------------------------
__global__ __launch_bounds__(128, 2) void k_gemm2(
    const unsigned short* __restrict__ ionew,
    const unsigned short* __restrict__ w2s,
    const float* __restrict__ b4,
    float* __restrict__ out)
{
    __shared__ __align__(16) char lds[3][12288];   // A @0 (4KB), B @4096 (8KB)

    const int tid = threadIdx.x, b = blockIdx.x;
    const int xcd = b & 7, q = b >> 3;             // q 0..63
    const int m0 = ((xcd << 5) | (q & 31)) << 5;   // rows match writer XCD
    const int n0 = (q >> 5) << 6;                  // 0 / 64

    const int lane = tid & 63, wid = tid >> 6;     // wid 0..1
    const int li = lane & 15, lh = lane >> 4;

    // A: 32 rows x 8 chunks; B: 64 rows x 8 chunks (both pre-swizzled global)
    int a_off[2], b_off[4];
    #pragma unroll
    for (int j = 0; j < 2; ++j) {
        int r = (wid << 4) + (j << 3) + (lane >> 3);      // A row 0..31
        a_off[j] = (m0 + r) * 512 + ((lane & 7) << 3);
    }
    #pragma unroll
    for (int j = 0; j < 4; ++j) {
        int r = (wid << 5) + (j << 3) + (lane >> 3);      // B row 0..63
        b_off[j] = (n0 + r) * 512 + ((lane & 7) << 3);
    }

    f32x4 zz = {0.f, 0.f, 0.f, 0.f};
    f32x4 acc[2][2];
    acc[0][0] = zz; acc[0][1] = zz; acc[1][0] = zz; acc[1][1] = zz;

#define STAGE2(KT, BUF) do {                                                   \
        int K_ = (KT);                                                         \
        char* A_ = (BUF); char* B_ = (BUF) + 4096;                             \
        _Pragma("unroll")                                                      \
        for (int j = 0; j < 2; ++j)                                            \
            gload16(ionew + a_off[j] + (K_ << 6),                              \
                    A_ + (wid << 11) + (j << 10));                             \
        _Pragma("unroll")                                                      \
        for (int j = 0; j < 4; ++j)                                            \
            gload16(w2s + b_off[j] + (K_ << 6),                                \
                    B_ + (wid << 12) + (j << 10));                             \
    } while (0)

#define COMPUTE2(BUF) do {                                                     \
        const char* A_ = (BUF); const char* B_ = (BUF) + 4096;                 \
        _Pragma("unroll")                                                      \
        for (int ks = 0; ks < 2; ++ks) {                                       \
            int c = ks * 4 + lh;                                               \
            bf16x8 av[2];                                                      \
            _Pragma("unroll")                                                  \
            for (int mi = 0; mi < 2; ++mi) {                                   \
                int r = mi * 16 + li;                                          \
                av[mi] = *(const bf16x8*)(A_ + r * 128 + ((c ^ (r & 7)) << 4));\
            }                                                                  \
            _Pragma("unroll")                                                  \
            for (int nj = 0; nj < 2; ++nj) {                                   \
                int rb = (wid << 5) + nj * 16 + li;                            \
                bf16x8 bv = *(const bf16x8*)(B_ + rb * 128 +                   \
                                             ((c ^ (rb & 7)) << 4));           \
                acc[0][nj] = __builtin_amdgcn_mfma_f32_16x16x32_bf16(          \
                    av[0], bv, acc[0][nj], 0, 0, 0);                           \
                acc[1][nj] = __builtin_amdgcn_mfma_f32_16x16x32_bf16(          \
                    av[1], bv, acc[1][nj], 0, 0, 0);                           \
            }                                                                  \
        }                                                                      \
    } while (0)

    STAGE2(0, lds[0]);
    STAGE2(1, lds[1]);
    char* p0 = lds[0]; char* p1 = lds[1]; char* p2 = lds[2];
    #pragma unroll 1
    for (int t = 0; t < 7; ++t) {
        WAITB(6);
        if (t + 2 < 8) STAGE2(t + 2, p2);
        COMPUTE2(p0);
        char* tmp = p0; p0 = p1; p1 = p2; p2 = tmp;
    }
    WAITB(0);
    COMPUTE2(p0);                          // tile 7
#undef STAGE2
#undef COMPUTE2

    #pragma unroll
    for (int nj = 0; nj < 2; ++nj) {
        int n = n0 + (wid << 5) + nj * 16 + li;
        float bb = b4[n];
        #pragma unroll
        for (int mi = 0; mi < 2; ++mi) {
            #pragma unroll
            for (int r = 0; r < 4; ++r) {
                int gm = m0 + mi * 16 + (lh << 2) + r;
                out[(size_t)gm * 128 + n] = tanh_fast(acc[mi][nj][r] + bb);
            }
        }
    }
}

// ---------------------------------------------------------------------------
extern "C" void kernel_launch(void* const* d_in, const int* in_sizes, int n_in,
                              void* d_out, int out_size, void* d_ws, size_t ws_size,
                              hipStream_t stream)
{
    const float* x      = (const float*)d_in[0];
    const float* io     = (const float*)d_in[1];
    const float* cf     = (const float*)d_in[2];
    // d_in[3] cs_state: dead (does not feed y)
    const float* Wi2io  = (const float*)d_in[4];
    const float* bi2io  = (const float*)d_in[5];
    const float* Wio2o  = (const float*)d_in[6];
    const float* bio2o  = (const float*)d_in[7];
    const float* Wio2io = (const float*)d_in[8];
    const float* bio2io = (const float*)d_in[9];
    const float* Wcf2io = (const float*)d_in[12];
    const float* bcf2io = (const float*)d_in[13];
    float* out = (float*)d_out;

    // ws: wcat 1,179,648 | w2s 131,072 | bsum 2,048 | ionew 8,388,608
    char* ws = (char*)d_ws;
    unsigned short* wcat  = (unsigned short*)ws;
    unsigned short* w2s   = (unsigned short*)(ws + 1179648);
    float*          bsum  = (float*)(ws + 1310720);
    unsigned short* ionew = (unsigned short*)(ws + 1312768);

    hipLaunchKernelGGL(k_convert, dim3(642), dim3(256), 0, stream,
                       Wi2io, Wio2io, Wcf2io, Wio2o, bi2io, bio2io, bcf2io,
                       wcat, w2s, bsum);
    hipLaunchKernelGGL(k_gemm1, dim3(512), dim3(256), 0, stream,
                       x, io, cf, wcat, bsum, ionew);
    hipLaunchKernelGGL(k_gemm2, dim3(512), dim3(128), 0, stream,
                       ionew, w2s, bio2o, out);
}